// Round 6
// baseline (213.136 us; speedup 1.0000x reference)
//
#include <hip/hip_runtime.h>
#include <math.h>

// Problem constants (AttentionLikeModel_75531294867774)
#define DIMM    1024
#define NHEADS  16
#define HDIM    64
#define BATCH   2
#define SEQ     2048
#define ROWS    (BATCH*SEQ)   // 4096

typedef _Float16 f16x8 __attribute__((ext_vector_type(8)));
typedef _Float16 f16x4 __attribute__((ext_vector_type(4)));
typedef float    f32x4 __attribute__((ext_vector_type(4)));

__device__ inline void gl_lds16(const void* g, void* l) {
    __builtin_amdgcn_global_load_lds(
        (const __attribute__((address_space(1))) void*)g,
        (__attribute__((address_space(3))) void*)l, 16, 0, 0);
}

// ---------------------------------------------------------------------------
// Merged prep: blocks [0,2048) cvt x -> fp16; [2048,2816) W_qkv^T; [2816,3072) W_out^T
// ---------------------------------------------------------------------------
__device__ void tcvt64(const float* __restrict__ in, _Float16* __restrict__ out,
                       int K, int N, int k0, int n0, float (*tile)[65], int t)
{
    {
        const int c4 = (t & 15) * 4;
        const int r  = t >> 4;
        #pragma unroll
        for (int i = 0; i < 4; i++) {
            const int rr = r + 16 * i;
            float4 v = *(const float4*)(in + (size_t)(k0 + rr) * N + n0 + c4);
            tile[rr][c4] = v.x; tile[rr][c4 + 1] = v.y;
            tile[rr][c4 + 2] = v.z; tile[rr][c4 + 3] = v.w;
        }
    }
    __syncthreads();
    #pragma unroll
    for (int i = 0; i < 2; i++) {
        const int seg = t + 256 * i;
        const int n   = seg >> 3;
        const int kc  = (seg & 7) * 8;
        f16x8 o;
        #pragma unroll
        for (int j = 0; j < 8; j++) o[j] = (_Float16)tile[kc + j][n];
        *(f16x8*)(out + (size_t)(n0 + n) * K + k0 + kc) = o;
    }
}

__global__ __launch_bounds__(256)
void prep_kernel(const float* __restrict__ x, const float* __restrict__ Wqkv,
                 const float* __restrict__ Wout, _Float16* __restrict__ xh,
                 _Float16* __restrict__ wqkvt, _Float16* __restrict__ woutt)
{
    __shared__ float tile[64][65];
    const int bx = blockIdx.x;
    const int t  = threadIdx.x;
    if (bx < 2048) {
        const int i = bx * 256 + t;
        const float4 a = *(const float4*)(x + (size_t)i * 8);
        const float4 b = *(const float4*)(x + (size_t)i * 8 + 4);
        f16x8 o;
        o[0] = (_Float16)a.x; o[1] = (_Float16)a.y; o[2] = (_Float16)a.z; o[3] = (_Float16)a.w;
        o[4] = (_Float16)b.x; o[5] = (_Float16)b.y; o[6] = (_Float16)b.z; o[7] = (_Float16)b.w;
        *(f16x8*)(xh + (size_t)i * 8) = o;
    } else if (bx < 2816) {
        const int id = bx - 2048;
        const int gx = id % 48, gy = id / 48;
        tcvt64(Wqkv, wqkvt, DIMM, 3 * DIMM, gy * 64, gx * 64, tile, t);
    } else {
        const int id = bx - 2816;
        const int gx = id & 15, gy = id >> 4;
        tcvt64(Wout, woutt, DIMM, DIMM, gy * 64, gx * 64, tile, t);
    }
}

// ---------------------------------------------------------------------------
// HGEMM + bias, BK=64. MODE 0: fp32 out. MODE 1: qkv — Q/K col-blocks write
// fp16 qkvh; V col-blocks (col0>=2048) write ONLY transposed vtg[bh][d][key]
// (fused V-transpose; qkvh V-third is never read).
// ---------------------------------------------------------------------------
template<int MODE>
__global__ __launch_bounds__(256)
void hgemm_bias_kernel(const _Float16* __restrict__ A, const _Float16* __restrict__ Bt,
                       const float* __restrict__ bias, void* __restrict__ Cout,
                       _Float16* __restrict__ vtg, int N, int K)
{
    __shared__ _Float16 As[128 * 64];
    __shared__ _Float16 Bs[128 * 64];

    const int t    = threadIdx.x;
    const int w    = t >> 6, lane = t & 63;
    const int quad = lane >> 4, l16 = lane & 15;
    const int wr   = w >> 1, wc = w & 1;
    const int row0 = blockIdx.y * 128, col0 = blockIdx.x * 128;
    const int sw   = l16 & 7;

    f32x4 acc[4][4];
    #pragma unroll
    for (int i = 0; i < 4; i++)
        #pragma unroll
        for (int j = 0; j < 4; j++)
            #pragma unroll
            for (int r = 0; r < 4; r++) acc[i][j][r] = 0.f;

    const _Float16* gA[4];
    const _Float16* gB[4];
    int lofs[4];
    #pragma unroll
    for (int j = 0; j < 4; j++) {
        const int s   = t + 256 * j;
        const int row = s >> 3;
        const int kb  = (s & 7) ^ (row & 7);
        gA[j] = A  + (size_t)(row0 + row) * K + kb * 8;
        gB[j] = Bt + (size_t)(col0 + row) * K + kb * 8;
        lofs[j] = s * 8;
    }

    const int niter = K >> 6;
    #pragma unroll 1
    for (int it = 0; it < niter; it++) {
        __syncthreads();
        #pragma unroll
        for (int j = 0; j < 4; j++) gl_lds16(gA[j], As + lofs[j]);
        #pragma unroll
        for (int j = 0; j < 4; j++) gl_lds16(gB[j], Bs + lofs[j]);
        #pragma unroll
        for (int j = 0; j < 4; j++) { gA[j] += 64; gB[j] += 64; }
        __syncthreads();

        f16x8 af[4][2], bf[4][2];
        #pragma unroll
        for (int i = 0; i < 4; i++) {
            const int arow = wr * 64 + i * 16 + l16;
            const int brow = wc * 64 + i * 16 + l16;
            #pragma unroll
            for (int hh = 0; hh < 2; hh++) {
                af[i][hh] = *(const f16x8*)(As + (arow * 8 + ((hh * 4 + quad) ^ sw)) * 8);
                bf[i][hh] = *(const f16x8*)(Bs + (brow * 8 + ((hh * 4 + quad) ^ sw)) * 8);
            }
        }
        #pragma unroll
        for (int i = 0; i < 4; i++)
            #pragma unroll
            for (int j = 0; j < 4; j++) {
                acc[i][j] = __builtin_amdgcn_mfma_f32_16x16x32_f16(af[i][0], bf[j][0], acc[i][j], 0, 0, 0);
                acc[i][j] = __builtin_amdgcn_mfma_f32_16x16x32_f16(af[i][1], bf[j][1], acc[i][j], 0, 0, 0);
            }
    }

    const bool vblock = (MODE == 1) && (col0 >= 2 * DIMM);
    #pragma unroll
    for (int j = 0; j < 4; j++) {
        const int col = col0 + wc * 64 + j * 16 + l16;
        const float bv = bias[col];
        #pragma unroll
        for (int i = 0; i < 4; i++) {
            const int row = row0 + wr * 64 + i * 16 + quad * 4;
            if (vblock) {
                // V block: write transposed into vtg[bh][d][key], 4 keys per b64
                const int dg  = col - 2 * DIMM;
                const int h   = dg >> 6, dl = dg & 63;
                const int b   = row >> 11, key = row & (SEQ - 1);
                f16x4 o;
                #pragma unroll
                for (int r = 0; r < 4; r++) o[r] = (_Float16)(acc[i][j][r] + bv);
                *(f16x4*)(vtg + ((size_t)((b * NHEADS + h) * 64 + dl)) * SEQ + key) = o;
            } else {
                #pragma unroll
                for (int r = 0; r < 4; r++) {
                    const float v = acc[i][j][r] + bv;
                    if (MODE == 1)
                        ((_Float16*)Cout)[(size_t)(row + r) * N + col] = (_Float16)v;
                    else
                        ((float*)Cout)[(size_t)(row + r) * N + col] = v;
                }
            }
        }
    }
}

// ---------------------------------------------------------------------------
// MFMA flash attention, q-tile = 128 (2 blocks/CU). Block = 4 waves = one
// (b,h,128-q tile); grid (16,32). Per 64-key tile: wave w owns keys
// [16w,16w+16) for S^T over all 128 q (8 qb MFMA-pairs), then PV for q-strip
// [32w,32w+32) over all 64 d. Q fragments register-resident (16 f16x8).
// Staged K/V serve 2x the FLOPs of the R5 version; barriers per work halved.
// LDS: K 8K + Vt 8K + P 18K = 34.4 KB.
// ---------------------------------------------------------------------------
__global__ __launch_bounds__(256, 2)
void flash_attn_kernel(const _Float16* __restrict__ qkv,
                       const _Float16* __restrict__ vtg,
                       _Float16* __restrict__ out)
{
    const int qt = blockIdx.x;          // 0..15
    const int bh = blockIdx.y;          // 0..31
    const int b  = bh >> 4, h = bh & 15;
    const int t    = threadIdx.x;
    const int w    = t >> 6;
    const int lane = t & 63;
    const int quad = lane >> 4;
    const int l16  = lane & 15;
    const int sw   = l16 & 7;

    __shared__ __align__(16) _Float16 Ks [64 * 64];
    __shared__ __align__(16) _Float16 Vts[64 * 64];
    __shared__ __align__(16) _Float16 Ps [128 * 72];

    const int q0 = qt * 128;
    const size_t rstr = 3 * DIMM;
    const _Float16* qbase = qkv + (size_t)b * SEQ * rstr;

    // ---- Q fragments: register-resident for the whole k-loop (8 qb strips)
    f16x8 qf[8][2];
    #pragma unroll
    for (int qb = 0; qb < 8; qb++) {
        const _Float16* qrow = qbase + (size_t)(q0 + qb * 16 + l16) * rstr + h * HDIM;
        qf[qb][0] = *(const f16x8*)(qrow + quad * 8);
        qf[qb][1] = *(const f16x8*)(qrow + 32 + quad * 8);
    }

    f32x4 Oacc[2][4];
    #pragma unroll
    for (int ss = 0; ss < 2; ss++)
        #pragma unroll
        for (int i = 0; i < 4; i++) Oacc[ss][i] = (f32x4){0.f, 0.f, 0.f, 0.f};
    float lrow[8];
    #pragma unroll
    for (int qb = 0; qb < 8; qb++) lrow[qb] = 0.f;

    // staging descriptors (two 16B segments each for K and Vt per thread)
    const int seg0 = t, seg1 = t + 256;
    const int r0 = seg0 >> 3, lb0 = (seg0 & 7) ^ (r0 & 7);
    const int r1 = seg1 >> 3, lb1 = (seg1 & 7) ^ (r1 & 7);
    const _Float16* gK0 = qbase + (size_t)r0 * rstr + DIMM + h * HDIM + lb0 * 8;
    const _Float16* gK1 = qbase + (size_t)r1 * rstr + DIMM + h * HDIM + lb1 * 8;
    const _Float16* gV0 = vtg + ((size_t)bh * 64 + r0) * SEQ + lb0 * 8;
    const _Float16* gV1 = vtg + ((size_t)bh * 64 + r1) * SEQ + lb1 * 8;

    const int kAbase = (16 * w + l16) * 64;

    #pragma unroll 1
    for (int k0 = 0; k0 < SEQ; k0 += 64) {
        __syncthreads();                        // prior PV/P reads done
        gl_lds16(gK0 + (size_t)k0 * rstr, Ks  + seg0 * 8);
        gl_lds16(gK1 + (size_t)k0 * rstr, Ks  + seg1 * 8);
        gl_lds16(gV0 + k0,                Vts + seg0 * 8);
        gl_lds16(gV1 + k0,                Vts + seg1 * 8);
        __syncthreads();                        // staging drained

        // ---- S^T strip: keys [16w,16w+16) x 128 q
        f16x8 kf0 = *(const f16x8*)(Ks + kAbase + ((0 + quad) ^ sw) * 8);
        f16x8 kf1 = *(const f16x8*)(Ks + kAbase + ((4 + quad) ^ sw) * 8);
        #pragma unroll
        for (int qb = 0; qb < 8; qb++) {
            f32x4 s = (f32x4){0.f, 0.f, 0.f, 0.f};
            s = __builtin_amdgcn_mfma_f32_16x16x32_f16(kf0, qf[qb][0], s, 0, 0, 0);
            s = __builtin_amdgcn_mfma_f32_16x16x32_f16(kf1, qf[qb][1], s, 0, 0, 0);
            float p0 = __expf(s[0] * 0.125f);
            float p1 = __expf(s[1] * 0.125f);
            float p2 = __expf(s[2] * 0.125f);
            float p3 = __expf(s[3] * 0.125f);
            lrow[qb] += (p0 + p1) + (p2 + p3);
            f16x4 pk;
            pk[0] = (_Float16)p0; pk[1] = (_Float16)p1;
            pk[2] = (_Float16)p2; pk[3] = (_Float16)p3;
            *(f16x4*)(Ps + (qb * 16 + l16) * 72 + 16 * w + 4 * quad) = pk;
        }
        __syncthreads();                        // P complete, K reads done

        // ---- O += P · V^T : q-strip [32w,32w+32) x 64 d
        f16x8 vf[4][2];
        #pragma unroll
        for (int db = 0; db < 4; db++) {
            const int vrow = db * 16 + l16;
            vf[db][0] = *(const f16x8*)(Vts + vrow * 64 + ((0 + quad) ^ sw) * 8);
            vf[db][1] = *(const f16x8*)(Vts + vrow * 64 + ((4 + quad) ^ sw) * 8);
        }
        #pragma unroll
        for (int ss = 0; ss < 2; ss++) {
            const int prow = ((2 * w + ss) * 16 + l16) * 72;
            f16x8 pf0 = *(const f16x8*)(Ps + prow + quad * 8);
            f16x8 pf1 = *(const f16x8*)(Ps + prow + 32 + quad * 8);
            #pragma unroll
            for (int db = 0; db < 4; db++) {
                Oacc[ss][db] = __builtin_amdgcn_mfma_f32_16x16x32_f16(pf0, vf[db][0], Oacc[ss][db], 0, 0, 0);
                Oacc[ss][db] = __builtin_amdgcn_mfma_f32_16x16x32_f16(pf1, vf[db][1], Oacc[ss][db], 0, 0, 0);
            }
        }
    }

    // ---- softmax denominator: reduce over quads, then waves (via LDS)
    #pragma unroll
    for (int qb = 0; qb < 8; qb++) {
        lrow[qb] += __shfl_xor(lrow[qb], 16);
        lrow[qb] += __shfl_xor(lrow[qb], 32);
    }
    __syncthreads();                            // all PV done; Ks reusable
    float* lbuf = (float*)Ks;                   // 4 x 128 floats
    if (lane < 16) {
        #pragma unroll
        for (int qb = 0; qb < 8; qb++) lbuf[w * 128 + qb * 16 + lane] = lrow[qb];
    }
    __syncthreads();
    #pragma unroll
    for (int ss = 0; ss < 2; ss++) {
        const int qloc = 32 * w + ss * 16 + quad * 4;
        float lrec[4];
        #pragma unroll
        for (int r = 0; r < 4; r++) {
            const int q = qloc + r;
            lrec[r] = 1.f / (lbuf[q] + lbuf[128 + q] + lbuf[256 + q] + lbuf[384 + q]);
        }
        #pragma unroll
        for (int db = 0; db < 4; db++) {
            #pragma unroll
            for (int r = 0; r < 4; r++) {
                out[(size_t)(b * SEQ + q0 + qloc + r) * DIMM + h * HDIM + db * 16 + l16] =
                    (_Float16)(Oacc[ss][db][r] * lrec[r]);
            }
        }
    }
}

// ---------------------------------------------------------------------------
extern "C" void kernel_launch(void* const* d_in, const int* in_sizes, int n_in,
                              void* d_out, int out_size, void* d_ws, size_t ws_size,
                              hipStream_t stream)
{
    const float* x    = (const float*)d_in[0];   // [2,2048,1024]
    const float* Wqkv = (const float*)d_in[1];   // [1024,3072]
    const float* bqkv = (const float*)d_in[2];   // [3072]
    const float* Wout = (const float*)d_in[3];   // [1024,1024]
    const float* bout = (const float*)d_in[4];   // [1024]
    float* out = (float*)d_out;                  // [2,2048,1024]

    _Float16* qkvh  = (_Float16*)d_ws;                   // 4096x3072 (V third unused)
    _Float16* attnh = qkvh  + (size_t)ROWS * 3 * DIMM;   // 4096x1024
    _Float16* xh    = attnh + (size_t)ROWS * DIMM;       // 4096x1024
    _Float16* wqkvt = xh    + (size_t)ROWS * DIMM;       // 3072x1024
    _Float16* woutt = wqkvt + (size_t)3 * DIMM * DIMM;   // 1024x1024
    _Float16* vtg   = woutt + (size_t)DIMM * DIMM;       // 32 x 64 x 2048

    // 0) merged fp16 conversions (x, W_qkv^T, W_out^T)
    prep_kernel<<<3072, 256, 0, stream>>>(x, Wqkv, Wout, xh, wqkvt, woutt);
    // 1) qkv = x @ W_qkv + b_qkv   (Q/K -> qkvh f16; V -> vtg transposed)
    {
        dim3 grid(3 * DIMM / 128, ROWS / 128);
        hgemm_bias_kernel<1><<<grid, 256, 0, stream>>>(xh, wqkvt, bqkv, qkvh, vtg, 3 * DIMM, DIMM);
    }
    // 2) attention -> attnh (fp16)
    {
        dim3 grid(SEQ / 128, BATCH * NHEADS);    // (16,32)
        flash_attn_kernel<<<grid, 256, 0, stream>>>(qkvh, vtg, attnh);
    }
    // 3) out = attn @ W_out + b_out  (fp32 out)
    {
        dim3 grid(DIMM / 128, ROWS / 128);
        hgemm_bias_kernel<0><<<grid, 256, 0, stream>>>(attnh, woutt, bout, out, nullptr, DIMM, DIMM);
    }
}